// Round 15
// baseline (10787.173 us; speedup 1.0000x reference)
//
#include <hip/hip_runtime.h>

#define SEQ   2048
#define EMBD  512
#define HID   512
#define NSL   128   // role-slices per layer
#define NTHR  256

typedef __attribute__((ext_vector_type(8))) short bf16x8;
typedef __attribute__((ext_vector_type(4))) float f32x4;

__device__ __forceinline__ float sigf(float x) { return 1.0f / (1.0f + __expf(-x)); }
__device__ __forceinline__ float tanhf_fast(float x) {
    float e = __expf(2.0f * x);
    return (e - 1.0f) / (e + 1.0f);
}
__device__ __forceinline__ short f2bf(float f) {
    unsigned u = __float_as_uint(f);
    unsigned r = (u + 0x7FFFu + ((u >> 16) & 1u)) >> 16;
    return (short)r;
}
__device__ __forceinline__ float bf2f(unsigned short s) {
    return __uint_as_float(((unsigned)s) << 16);
}
__device__ __forceinline__ bf16x8 cvt8(float4 a, float4 b) {
    bf16x8 r;
    r[0] = f2bf(a.x); r[1] = f2bf(a.y); r[2] = f2bf(a.z); r[3] = f2bf(a.w);
    r[4] = f2bf(b.x); r[5] = f2bf(b.y); r[6] = f2bf(b.z); r[7] = f2bf(b.w);
    return r;
}

// ---- single prep node (3 merged): blocks 0-255 repack weights (8 MB),
// blocks 256-511 transpose tokens; blocks 496-511 also pre-add biases.
__global__ __launch_bounds__(NTHR, 1) void prep_all(
    const float* __restrict__ w_ih, const float* __restrict__ w_hh,
    const int* __restrict__ tokens,
    const float* __restrict__ b_ih, const float* __restrict__ b_hh,
    bf16x8* __restrict__ wsW, int* __restrict__ tokT, float* __restrict__ wsB)
{
    const int blk = blockIdx.x, tid = threadIdx.x;
    if (blk < 256) {
        const int role = blk;
        const bool l1 = (role >= NSL);
        const int s   = l1 ? (role - NSL) : role;
        const int layer = l1 ? 1 : 0;
        const int w = tid >> 6, lane = tid & 63, i16 = lane & 15, hi = lane >> 4;
        const int kb = (w & 1) * 256;
        const bool xw = (w < 2);
        const int gg_ = i16 >> 2, jj_ = i16 & 3;
        const int rowg = gg_ * 512 + s * 4 + jj_;
        const float* wbase = xw ? (w_ih + ((size_t)layer * 2048 + rowg) * 512)
                                : (w_hh + ((size_t)layer * 2048 + rowg) * 512);
        #pragma unroll
        for (int q = 0; q < 8; ++q) {
            int koff = kb + q * 32 + hi * 8;
            wsW[(((size_t)role * 4 + w) * 8 + q) * 64 + lane] =
                cvt8(*(const float4*)(wbase + koff), *(const float4*)(wbase + koff + 4));
        }
    } else {
        const int idx = (blk - 256) * NTHR + tid;   // 65536 token slots
        tokT[idx] = tokens[(idx & 31) * SEQ + (idx >> 5)];
        if (blk >= 496) {
            const int bidx = (blk - 496) * NTHR + tid;   // 4096 biases
            wsB[bidx] = b_ih[bidx] + b_hh[bidx];
        }
    }
}

// ---- one timestep node, 512 WGs: wg>>1 = role (0-127: L0 step k; 128-255:
// L1 step k-1), wg&1 = batch half. 4 waves x 8 MFMAs (two 4-deep acc chains).
// Inter-node ordering + coherence from the graph edge; no atomics/polls.
__global__ __launch_bounds__(NTHR, 1) void lstm_step(
    int k,
    const int*   __restrict__ tokT, const float* __restrict__ emb,
    const bf16x8* __restrict__ wsW, const float* __restrict__ wsB,
    unsigned short* __restrict__ h16, float* __restrict__ cbuf)
{
    __shared__ float part[4][16][17];   // [wave(K-partial)][m][batch] +1 pad (bank-conflict-free reads)

    const int wg  = blockIdx.x, tid = threadIdx.x;
    const int role = wg >> 1, bo = (wg & 1) << 4;
    const bool l1 = (role >= NSL);
    const int s   = l1 ? (role - NSL) : role;
    const int layer = l1 ? 1 : 0;
    const int t = l1 ? (k - 1) : k;
    if (t < 0 || t >= SEQ) return;      // uniform per WG
    const int p = t & 1;

    const int w = tid >> 6, lane = tid & 63, i16 = lane & 15, hi = lane >> 4;
    const int kb = (w & 1) * 256;
    const bool xw = (w < 2);

    unsigned short* const h0a_ = h16;
    unsigned short* const h0b_ = h16 + 16384;
    unsigned short* const h1a_ = h16 + 32768;
    unsigned short* const h1b_ = h16 + 49152;

    // A fragments: coalesced 16B loads, L2-resident across nodes
    bf16x8 A[8];
    const bf16x8* wp = wsW + (((size_t)role * 4 + w) * 8) * 64 + lane;
    #pragma unroll
    for (int q = 0; q < 8; ++q) A[q] = wp[q * 64];

    // B source (proven pipelining):
    //  L0: xw -> x_t gather ; else h0[t-1].  L1: xw -> h0[t] ; else h1[t-1].
    const unsigned short* bsrc;
    if (!l1) bsrc = xw ? (const unsigned short*)nullptr : (p ? h0a_ : h0b_);
    else     bsrc = xw ? (p ? h0b_ : h0a_) : (p ? h1a_ : h1b_);

    // two independent accumulator chains (halved MFMA dependency latency)
    f32x4 a0 = {0.f, 0.f, 0.f, 0.f};
    f32x4 a1 = {0.f, 0.f, 0.f, 0.f};

    if (bsrc == nullptr) {
        const size_t r0 = (size_t)tokT[t * 32 + bo + i16] * EMBD;   // 1 coalesced line
        #pragma unroll
        for (int q = 0; q < 4; ++q) {
            int koff = kb + q * 32 + hi * 8;
            float4 xa = *(const float4*)(emb + r0 + koff);
            float4 xb = *(const float4*)(emb + r0 + koff + 4);
            a0 = __builtin_amdgcn_mfma_f32_16x16x32_bf16(A[q], cvt8(xa, xb), a0, 0, 0, 0);
        }
        #pragma unroll
        for (int q = 4; q < 8; ++q) {
            int koff = kb + q * 32 + hi * 8;
            float4 xa = *(const float4*)(emb + r0 + koff);
            float4 xb = *(const float4*)(emb + r0 + koff + 4);
            a1 = __builtin_amdgcn_mfma_f32_16x16x32_bf16(A[q], cvt8(xa, xb), a1, 0, 0, 0);
        }
    } else {
        const unsigned short* pb = bsrc + (size_t)(bo + i16) * 512 + kb;
        #pragma unroll
        for (int q = 0; q < 4; ++q) {
            bf16x8 B = *(const bf16x8*)(pb + q * 32 + hi * 8);
            a0 = __builtin_amdgcn_mfma_f32_16x16x32_bf16(A[q], B, a0, 0, 0, 0);
        }
        #pragma unroll
        for (int q = 4; q < 8; ++q) {
            bf16x8 B = *(const bf16x8*)(pb + q * 32 + hi * 8);
            a1 = __builtin_amdgcn_mfma_f32_16x16x32_bf16(A[q], B, a1, 0, 0, 0);
        }
    }
    const f32x4 acc = a0 + a1;

    // C mapping (verified): col = lane&15 (batch-in-block), row = hi*4 + reg
    #pragma unroll
    for (int r = 0; r < 4; ++r) part[w][hi * 4 + r][i16] = acc[r];
    __syncthreads();

    // cell update: 64 threads, one (col, batch) cell each
    if (tid < 64) {
        const int jj = tid >> 4, bb = tid & 15, eb = bo + bb;
        float g4[4];
        #pragma unroll
        for (int g = 0; g < 4; ++g)
            g4[g] = part[0][g * 4 + jj][bb] + part[1][g * 4 + jj][bb]
                  + part[2][g * 4 + jj][bb] + part[3][g * 4 + jj][bb]
                  + wsB[layer * 2048 + g * 512 + s * 4 + jj];
        float* cp = cbuf + layer * 16384 + eb * 512 + s * 4 + jj;
        float c = *cp;
        // gate order: i, f, g, o
        c = sigf(g4[1]) * c + sigf(g4[0]) * tanhf_fast(g4[2]);
        const float h = sigf(g4[3]) * tanhf_fast(c);
        *cp = c;
        unsigned short* hout = l1 ? (p ? h1b_ : h1a_) : (p ? h0b_ : h0a_);
        hout[eb * 512 + s * 4 + jj] = (unsigned short)f2bf(h);
    }
}

__global__ void fc_head(const unsigned short* __restrict__ h1fin,
                        const float* __restrict__ fc_w,
                        const float* __restrict__ fc_b,
                        float* __restrict__ out)
{
    const int tid = threadIdx.x;
    if (tid >= 64) return;
    const int b = tid >> 1, o = tid & 1;
    float acc = 0.f;
    for (int j = 0; j < HID; ++j)
        acc += bf2f(h1fin[b * 512 + j]) * fc_w[o * HID + j];
    out[b * 2 + o] = sigf(acc + fc_b[o]);
}

extern "C" void kernel_launch(void* const* d_in, const int* in_sizes, int n_in,
                              void* d_out, int out_size, void* d_ws, size_t ws_size,
                              hipStream_t stream)
{
    const int*   tokens = (const int*)d_in[0];
    const float* emb    = (const float*)d_in[1];
    const float* w_ih   = (const float*)d_in[2];
    const float* w_hh   = (const float*)d_in[3];
    const float* b_ih   = (const float*)d_in[4];
    const float* b_hh   = (const float*)d_in[5];
    const float* fc_w   = (const float*)d_in[6];
    const float* fc_b   = (const float*)d_in[7];

    // ---- workspace layout (disjoint, verified by arithmetic):
    //   +0        wsB   16 KB   (pre-added biases; 4096 f32)
    //   +65536    h16   128 KB  (4 x 32 KB h buffers, bf16 [b][j])
    //   +196608   cbuf  128 KB  (2 x 64 KB f32 c state)
    //   +327680   tokT  256 KB  ([T][32] token table)
    //   +589824   wsW   8 MB    (ALL bf16 weight fragments: 256 roles x 32 KB)
    //   total ~8.98 MB (proven fit in R12/R14)
    float*          wsB  = (float*)d_ws;
    unsigned short* h16  = (unsigned short*)((char*)d_ws + 65536);
    float*          cbuf = (float*)((char*)d_ws + 196608);
    int*            tokT = (int*)((char*)d_ws + 327680);
    bf16x8*         wsW  = (bf16x8*)((char*)d_ws + 589824);

    // zero h (h[-1]=0) and c
    hipMemsetAsync((char*)d_ws + 65536, 0, 262144, stream);
    prep_all<<<dim3(512), dim3(NTHR), 0, stream>>>(
        w_ih, w_hh, tokens, b_ih, b_hh, wsW, tokT, wsB);

    for (int k = 0; k <= SEQ; ++k)
        lstm_step<<<dim3(512), dim3(NTHR), 0, stream>>>(
            k, tokT, emb, wsW, wsB, h16, cbuf);

    // h1 final: t=2047, parity 1 -> h1b
    fc_head<<<dim3(1), dim3(64), 0, stream>>>(h16 + 49152, fc_w, fc_b, (float*)d_out);
}